// Round 9
// baseline (83.201 us; speedup 1.0000x reference)
//
#include <hip/hip_runtime.h>
#include <math.h>

// LogPolar resample: data (32,3,512,512) f32 -> out (32,3,512,512) f32.
//
// R9 = R8 + plane-temporal block ordering (g slowest within each XCD).
//  1) table_kernel (2 blocks): rad (j-only), cos/sin (i-only) -> 3*512 floats
//     in d_ws; correctly-rounded f32 via f64 libm, bit-identical to the
//     validated chain (trunc/mask decisions are discontinuous).
//  2) resample_kernel (32768 blocks, PPB=3, NG=32):
//     - 4theta x 64j tile per block (R8): 4 waves share a j-window on
//       adjacent rays -> gather line sharing.
//     - NEW: b&7 = xcd, s = b>>3, g = ((s>>10)<<3)|xcd, pixblock = s&1023.
//       XCD k processes plane-groups {k, k+8, k+16, k+24} SEQUENTIALLY:
//       resident gather footprint = 3 planes (2.4 MB) < 4 MB L2, vs R8's
//       interleaved 12 planes (9.6 MB) thrashing to L3. Latency-bound gathers
//       should drop from L3 (~500cy) to L2 (~200cy) service.
//     - X,Y from tables with native f32 ops (bit-identical); f32 weights
//       (~1e-7 << 6.5e-2 threshold); nt stores.
//
// Ladder (graph us): R2 146 -> R4 101 -> R6 62.9 -> R7 79 (PPB=1 regressed:
// wave axis exhausted) -> R8 63.6 (tile reshape graph-neutral).
// Anti-lessons: float4 merge (R5), more waves past occ~73% (R7).

#define HW (512 * 512)
#define NPIX (512 * 512)
#define PLANES 96
#define PPB 3   // planes per resample block
#define NG 32   // plane groups (PLANES/PPB)

// ---------------- table kernel: 512 entries of rad/cos/sin ----------------
__global__ __launch_bounds__(256) void table_kernel(float* __restrict__ radT,
                                                    float* __restrict__ cT,
                                                    float* __restrict__ sT) {
  const int t = blockIdx.x * 256 + threadIdx.x;  // 0..511

  // max_r = log(sqrt(512^2+512^2)/2 * 700), all in f32 steps (CR via f64)
  const float sq_f = (float)sqrt(524288.0);             // f32 sqrt (CR)
  const float half_f = sq_f * 0.5f;                     // exact
  const float prod_f = (float)((double)half_f * 700.0); // f32 mul emulated
  const float maxr_f = (float)log((double)prod_f);      // f32 log (CR)

  // rad = exp(t * max_r / 512) in f32 steps
  const float t1 = (float)((double)(float)t * (double)maxr_f); // f32 mul
  const float tt = t1 * (1.0f / 512.0f);                       // exact (pow2)
  radT[t] = (float)exp((double)tt);                            // f32 exp (CR)

  // ang = t * 2.0 * f32(pi) / 512 in f32 steps
  const float two_i = (float)(2 * t);  // exact
  const float ang1 = (float)((double)two_i * (double)(float)M_PI); // f32 mul
  const float ang = ang1 * (1.0f / 512.0f);                        // exact
  cT[t] = (float)cos((double)ang);  // f32 cos (CR)
  sT[t] = (float)sin((double)ang);  // f32 sin (CR)
}

// ---------------- resample kernel ----------------
__global__ __launch_bounds__(256) void resample_kernel(
    const float* __restrict__ in, float* __restrict__ out,
    const float* __restrict__ radT, const float* __restrict__ cT,
    const float* __restrict__ sT) {
  const int b = (int)blockIdx.x;
  const int xcd = b & 7;
  const int s = b >> 3;                    // 0..4095 (within-XCD sequence)
  const int g = ((s >> 10) << 3) | xcd;    // plane group, slowest within XCD
  const int pixblock = s & 1023;           // 0..1023 (tile index)

  // 4theta x 64j tile: tiles laid out 128 (theta-groups) x 8 (j-windows)
  const int i = ((pixblock >> 3) << 2) + ((int)threadIdx.x >> 6);  // theta
  const int j = ((pixblock & 7) << 6) + ((int)threadIdx.x & 63);   // radius
  const int pix = i * 512 + j;

  const float rad = radT[j];
  const float c = cT[i];
  const float s_ = sT[i];

  // Native f32 ops == "exact in f64, round once" -> X,Y bit-identical to the
  // validated chain; all trunc/mask decisions follow from X,Y alone.
  const float X = __fadd_rn(256.0f, __fmul_rn(rad, c));
  const float Y = __fsub_rn(256.0f, __fmul_rn(rad, s_));

  const int p0 = g * PPB;
  float* op = out + (size_t)p0 * HW + pix;

  const bool inb = (X >= 0.0f) && (X < 512.0f) && (Y >= 0.0f) && (Y < 512.0f);
  if (!inb) {
#pragma unroll
    for (int p = 0; p < PPB; ++p) {
      __builtin_nontemporal_store(0.0f, op);
      op += HW;
    }
    return;
  }

  // corner indices (decisions from bit-exact X,Y) + f32 weights
  const int yd = (int)Y;  // trunc == floor for Y in [0,512)
  const int xd = (int)X;
  const int yu = min(yd + 1, 511);
  const int xu = min(xd + 1, 511);
  const float fyd = (Y - (float)yd) * (Y - (float)yd);
  const float fyu = (Y - (float)yu) * (Y - (float)yu);
  const float fxd = (X - (float)xd) * (X - (float)xd);
  const float fxu = (X - (float)xu) * (X - (float)xu);
  const float dd = fyd + fxd;
  const float du = fyd + fxu;
  const float ud = fyu + fxd;
  const float uu = fyu + fxu;
  const float inv = 1.0f / (dd + du + ud + uu);
  const float wdd = dd * inv;
  const float wdu = du * inv;
  const float wud = ud * inv;
  const float wuu = uu * inv;

  const int i00 = yd * 512 + xd;
  const int i01 = yd * 512 + xu;
  const int i10 = yu * 512 + xd;
  const int i11 = yu * 512 + xu;

  const float* ip = in + (size_t)p0 * HW;
#pragma unroll
  for (int p = 0; p < PPB; ++p) {
    const float v =
        wdd * ip[i00] + wdu * ip[i01] + wud * ip[i10] + wuu * ip[i11];
    __builtin_nontemporal_store(v, op);
    ip += HW;
    op += HW;
  }
}

// ---------------- fallback: proven R2 monolithic kernel ----------------
__global__ __launch_bounds__(256) void logpolar_mono(
    const float* __restrict__ in, float* __restrict__ out) {
  const int pix = blockIdx.x * 256 + threadIdx.x;
  const int i = pix >> 9;
  const int j = pix & 511;

  const float sq_f = (float)sqrt(524288.0);
  const float half_f = sq_f * 0.5f;
  const float prod_f = (float)((double)half_f * 700.0);
  const float maxr_f = (float)log((double)prod_f);
  const float t1 = (float)((double)(float)j * (double)maxr_f);
  const float t = t1 * (1.0f / 512.0f);
  const float rad_f = (float)exp((double)t);
  const float two_i = (float)(2 * i);
  const float ang1 = (float)((double)two_i * (double)(float)M_PI);
  const float ang = ang1 * (1.0f / 512.0f);
  const float c_f = (float)cos((double)ang);
  const float s_f = (float)sin((double)ang);
  const float X0 = (float)((double)rad_f * (double)c_f);
  const float Y0 = (float)((double)rad_f * (double)s_f);
  const float X = (float)(256.0 + (double)X0);
  const float Y = (float)(256.0 - (double)Y0);

  const bool inb = (X >= 0.0f) && (X < 512.0f) && (Y >= 0.0f) && (Y < 512.0f);

  float wdd = 0.f, wdu = 0.f, wud = 0.f, wuu = 0.f;
  int idd = 0, idu = 0, iud = 0, iuu = 0;
  if (inb) {
    const int yd = (int)Y;
    const int xd = (int)X;
    const int yu = min(yd + 1, 511);
    const int xu = min(xd + 1, 511);
    const double Xd = (double)X, Yd = (double)Y;
    const double dyd = (Yd - (double)yd) * (Yd - (double)yd);
    const double dyu = (Yd - (double)yu) * (Yd - (double)yu);
    const double dxd = (Xd - (double)xd) * (Xd - (double)xd);
    const double dxu = (Xd - (double)xu) * (Xd - (double)xu);
    const double dd = dyd + dxd;
    const double du = dyd + dxu;
    const double ud = dyu + dxd;
    const double uu = dyu + dxu;
    const double inv = 1.0 / (dd + du + ud + uu);
    wdd = (float)(dd * inv);
    wdu = (float)(du * inv);
    wud = (float)(ud * inv);
    wuu = (float)(uu * inv);
    idd = yd * 512 + xd;
    idu = yd * 512 + xu;
    iud = yu * 512 + xd;
    iuu = yu * 512 + xu;
  }

  const float* __restrict__ ip = in;
  float* __restrict__ op = out + pix;
#pragma unroll 4
  for (int p = 0; p < PLANES; ++p) {
    float v = 0.0f;
    if (inb) {
      v = wdd * ip[idd] + wdu * ip[idu] + wud * ip[iud] + wuu * ip[iuu];
    }
    *op = v;
    ip += HW;
    op += HW;
  }
}

extern "C" void kernel_launch(void* const* d_in, const int* in_sizes, int n_in,
                              void* d_out, int out_size, void* d_ws,
                              size_t ws_size, hipStream_t stream) {
  const float* in = (const float*)d_in[0];
  float* out = (float*)d_out;

  const size_t table_bytes = 3 * 512 * sizeof(float);  // 6 KB
  if (ws_size >= table_bytes) {
    float* radT = (float*)d_ws;
    float* cT = radT + 512;
    float* sT = cT + 512;
    table_kernel<<<dim3(2), dim3(256), 0, stream>>>(radT, cT, sT);
    resample_kernel<<<dim3((NPIX / 256) * NG), dim3(256), 0, stream>>>(
        in, out, radT, cT, sT);
  } else {
    logpolar_mono<<<dim3(NPIX / 256), dim3(256), 0, stream>>>(in, out);
  }
}

// Round 10
// 64.588 us; speedup vs baseline: 1.2882x; 1.2882x over previous
//
#include <hip/hip_runtime.h>
#include <math.h>

// LogPolar resample: data (32,3,512,512) f32 -> out (32,3,512,512) f32.
//
// R10 = R6 (best anchor, 62.9us) + straight-line 12-load inner body.
//
// KEY DIAGNOSIS (R6/R8 profiles): VGPR_Count == 16 -> the compiler
// SERIALIZED the plane loop (load4/wait/fma/store per plane) -> per-wave
// MLP ~= 4 loads, latency-bound at ~600cy avg gather service. Fix: issue all
// 4 corners x 3 planes = 12 gathers into NAMED scalars (no arrays, no
// runtime indexing -> stays in registers), then all FMAs, then all stores.
//
//  1) table_kernel (2 blocks): rad (j-only), cos/sin (i-only) -> 3*512 f32 in
//     d_ws; correctly-rounded f32 via f64 libm, bit-identical to the
//     validated chain (trunc/mask decisions are discontinuous -> must match
//     the np reference exactly).
//  2) resample_kernel (32768 blocks, PPB=3, NG=32, R6 mapping): X,Y from
//     tables with native f32 ops (bit-identical); f32 weights (~1e-7 error
//     << 6.5e-2 threshold); nt stores; g = blockIdx&31 interleave (R9's
//     plane-sequential ordering REGRESSED: footprint concentration ->
//     channel hotspotting; interleave restored).
//
// Ladder (graph us): R2 146 -> R4 101 -> R6 62.9 -> R7 79 (PPB=1: wave axis
// exhausted) -> R8 63.6 (tile reshape neutral) -> R9 83.2 (ordering: worse).

#define HW (512 * 512)
#define NPIX (512 * 512)
#define PLANES 96
#define PPB 3   // planes per resample block
#define NG 32   // plane groups (PLANES/PPB)

// ---------------- table kernel: 512 entries of rad/cos/sin ----------------
__global__ __launch_bounds__(256) void table_kernel(float* __restrict__ radT,
                                                    float* __restrict__ cT,
                                                    float* __restrict__ sT) {
  const int t = blockIdx.x * 256 + threadIdx.x;  // 0..511

  // max_r = log(sqrt(512^2+512^2)/2 * 700), all in f32 steps (CR via f64)
  const float sq_f = (float)sqrt(524288.0);             // f32 sqrt (CR)
  const float half_f = sq_f * 0.5f;                     // exact
  const float prod_f = (float)((double)half_f * 700.0); // f32 mul emulated
  const float maxr_f = (float)log((double)prod_f);      // f32 log (CR)

  // rad = exp(t * max_r / 512) in f32 steps
  const float t1 = (float)((double)(float)t * (double)maxr_f); // f32 mul
  const float tt = t1 * (1.0f / 512.0f);                       // exact (pow2)
  radT[t] = (float)exp((double)tt);                            // f32 exp (CR)

  // ang = t * 2.0 * f32(pi) / 512 in f32 steps
  const float two_i = (float)(2 * t);  // exact
  const float ang1 = (float)((double)two_i * (double)(float)M_PI); // f32 mul
  const float ang = ang1 * (1.0f / 512.0f);                        // exact
  cT[t] = (float)cos((double)ang);  // f32 cos (CR)
  sT[t] = (float)sin((double)ang);  // f32 sin (CR)
}

// ---------------- resample kernel ----------------
__global__ __launch_bounds__(256) void resample_kernel(
    const float* __restrict__ in, float* __restrict__ out,
    const float* __restrict__ radT, const float* __restrict__ cT,
    const float* __restrict__ sT) {
  const int g = blockIdx.x & (NG - 1);   // plane group; g&7 = XCD partition
  const int pixblock = blockIdx.x >> 5;  // 0..1023
  const int pix = pixblock * 256 + (int)threadIdx.x;
  const int i = pix >> 9;   // theta bin (block-uniform)
  const int j = pix & 511;  // radius bin

  const float rad = radT[j];
  const float c = cT[i];
  const float s = sT[i];

  // Native f32 ops == "exact in f64, round once" -> X,Y bit-identical to the
  // validated chain; all trunc/mask decisions follow from X,Y alone.
  const float X = __fadd_rn(256.0f, __fmul_rn(rad, c));
  const float Y = __fsub_rn(256.0f, __fmul_rn(rad, s));

  const int p0 = g * PPB;
  float* op = out + (size_t)p0 * HW + pix;

  const bool inb = (X >= 0.0f) && (X < 512.0f) && (Y >= 0.0f) && (Y < 512.0f);
  if (!inb) {
    __builtin_nontemporal_store(0.0f, op);
    __builtin_nontemporal_store(0.0f, op + HW);
    __builtin_nontemporal_store(0.0f, op + 2 * HW);
    return;
  }

  // corner indices (decisions from bit-exact X,Y) + f32 weights
  const int yd = (int)Y;  // trunc == floor for Y in [0,512)
  const int xd = (int)X;
  const int yu = min(yd + 1, 511);
  const int xu = min(xd + 1, 511);
  const float fyd = (Y - (float)yd) * (Y - (float)yd);
  const float fyu = (Y - (float)yu) * (Y - (float)yu);
  const float fxd = (X - (float)xd) * (X - (float)xd);
  const float fxu = (X - (float)xu) * (X - (float)xu);
  const float dd = fyd + fxd;
  const float du = fyd + fxu;
  const float ud = fyu + fxd;
  const float uu = fyu + fxu;
  const float inv = 1.0f / (dd + du + ud + uu);
  const float wdd = dd * inv;
  const float wdu = du * inv;
  const float wud = ud * inv;
  const float wuu = uu * inv;

  const int i00 = yd * 512 + xd;
  const int i01 = yd * 512 + xu;
  const int i10 = yu * 512 + xd;
  const int i11 = yu * 512 + xu;

  // ---- straight-line: issue ALL 12 gathers, then math, then stores ----
  const float* ip0 = in + (size_t)p0 * HW;
  const float* ip1 = ip0 + HW;
  const float* ip2 = ip1 + HW;

  const float a0_00 = ip0[i00];
  const float a0_01 = ip0[i01];
  const float a0_10 = ip0[i10];
  const float a0_11 = ip0[i11];
  const float a1_00 = ip1[i00];
  const float a1_01 = ip1[i01];
  const float a1_10 = ip1[i10];
  const float a1_11 = ip1[i11];
  const float a2_00 = ip2[i00];
  const float a2_01 = ip2[i01];
  const float a2_10 = ip2[i10];
  const float a2_11 = ip2[i11];

  const float v0 = wdd * a0_00 + wdu * a0_01 + wud * a0_10 + wuu * a0_11;
  const float v1 = wdd * a1_00 + wdu * a1_01 + wud * a1_10 + wuu * a1_11;
  const float v2 = wdd * a2_00 + wdu * a2_01 + wud * a2_10 + wuu * a2_11;

  __builtin_nontemporal_store(v0, op);
  __builtin_nontemporal_store(v1, op + HW);
  __builtin_nontemporal_store(v2, op + 2 * HW);
}

// ---------------- fallback: proven R2 monolithic kernel ----------------
__global__ __launch_bounds__(256) void logpolar_mono(
    const float* __restrict__ in, float* __restrict__ out) {
  const int pix = blockIdx.x * 256 + threadIdx.x;
  const int i = pix >> 9;
  const int j = pix & 511;

  const float sq_f = (float)sqrt(524288.0);
  const float half_f = sq_f * 0.5f;
  const float prod_f = (float)((double)half_f * 700.0);
  const float maxr_f = (float)log((double)prod_f);
  const float t1 = (float)((double)(float)j * (double)maxr_f);
  const float t = t1 * (1.0f / 512.0f);
  const float rad_f = (float)exp((double)t);
  const float two_i = (float)(2 * i);
  const float ang1 = (float)((double)two_i * (double)(float)M_PI);
  const float ang = ang1 * (1.0f / 512.0f);
  const float c_f = (float)cos((double)ang);
  const float s_f = (float)sin((double)ang);
  const float X0 = (float)((double)rad_f * (double)c_f);
  const float Y0 = (float)((double)rad_f * (double)s_f);
  const float X = (float)(256.0 + (double)X0);
  const float Y = (float)(256.0 - (double)Y0);

  const bool inb = (X >= 0.0f) && (X < 512.0f) && (Y >= 0.0f) && (Y < 512.0f);

  float wdd = 0.f, wdu = 0.f, wud = 0.f, wuu = 0.f;
  int idd = 0, idu = 0, iud = 0, iuu = 0;
  if (inb) {
    const int yd = (int)Y;
    const int xd = (int)X;
    const int yu = min(yd + 1, 511);
    const int xu = min(xd + 1, 511);
    const double Xd = (double)X, Yd = (double)Y;
    const double dyd = (Yd - (double)yd) * (Yd - (double)yd);
    const double dyu = (Yd - (double)yu) * (Yd - (double)yu);
    const double dxd = (Xd - (double)xd) * (Xd - (double)xd);
    const double dxu = (Xd - (double)xu) * (Xd - (double)xu);
    const double dd = dyd + dxd;
    const double du = dyd + dxu;
    const double ud = dyu + dxd;
    const double uu = dyu + dxu;
    const double inv = 1.0 / (dd + du + ud + uu);
    wdd = (float)(dd * inv);
    wdu = (float)(du * inv);
    wud = (float)(ud * inv);
    wuu = (float)(uu * inv);
    idd = yd * 512 + xd;
    idu = yd * 512 + xu;
    iud = yu * 512 + xd;
    iuu = yu * 512 + xu;
  }

  const float* __restrict__ ip = in;
  float* __restrict__ op = out + pix;
#pragma unroll 4
  for (int p = 0; p < PLANES; ++p) {
    float v = 0.0f;
    if (inb) {
      v = wdd * ip[idd] + wdu * ip[idu] + wud * ip[iud] + wuu * ip[iuu];
    }
    *op = v;
    ip += HW;
    op += HW;
  }
}

extern "C" void kernel_launch(void* const* d_in, const int* in_sizes, int n_in,
                              void* d_out, int out_size, void* d_ws,
                              size_t ws_size, hipStream_t stream) {
  const float* in = (const float*)d_in[0];
  float* out = (float*)d_out;

  const size_t table_bytes = 3 * 512 * sizeof(float);  // 6 KB
  if (ws_size >= table_bytes) {
    float* radT = (float*)d_ws;
    float* cT = radT + 512;
    float* sT = cT + 512;
    table_kernel<<<dim3(2), dim3(256), 0, stream>>>(radT, cT, sT);
    resample_kernel<<<dim3((NPIX / 256) * NG), dim3(256), 0, stream>>>(
        in, out, radT, cT, sT);
  } else {
    logpolar_mono<<<dim3(NPIX / 256), dim3(256), 0, stream>>>(in, out);
  }
}

// Round 11
// 61.060 us; speedup vs baseline: 1.3626x; 1.0578x over previous
//
#include <hip/hip_runtime.h>
#include <math.h>

// LogPolar resample: data (32,3,512,512) f32 -> out (32,3,512,512) f32.
//
// R11 = R10 body + WAVE-LEVEL 2D tiling: wave = 4theta x 16j (was 1 x 64j).
//
// DIAGNOSIS CHAIN: R7 (3x waves: neutral), R10 (3x per-wave MLP: neutral),
// R9 (placement: regressed) -> the wall is gather LINE THROUGHPUT: a
// divergent wave-gather costs ~1 cyc per distinct 64B line in TA/L1.
// R6's wave = 64 consecutive j on ONE ray = a radial streak spanning
// rad -> 4.7*rad px = ~1 line/lane. New wave = 4 adjacent rays x 16 j:
// compact patch (radial span 4x smaller, rays 0.012*rad px apart) ->
// ~2-3x fewer distinct lines per gather at mid radius.
// Stores stay fully coalesced: wave-store = 4 rows x 16 consecutive floats
// = 4 full 64B lines.
//
//  1) table_kernel (2 blocks): rad (j-only), cos/sin (i-only) -> 3*512 f32,
//     correctly-rounded f32 via f64 libm (bit-identical map decisions).
//  2) resample_kernel (32768 blocks, PPB=3, NG=32, R6 grid/XCD mapping):
//     block tile = 4theta x 64j (R8's footprint); wave w covers
//     j in [tj+16w, tj+16w+16), theta in [ti, ti+4).
//     X,Y native f32 (bit-identical); f32 weights; straight-line 12-gather
//     body (R10); nt stores.
//
// Ladder (graph us): R2 146 -> R4 101 -> R6 62.9 -> R7 79 (waves: no) ->
// R8 63.6 (block tile: ~neutral) -> R9 83 (ordering: worse) -> R10 64.6
// (MLP: neutral). Anti-lessons: float4 merge (R5), wave scaling past
// occ~73% (R7), footprint concentration (R9).

#define HW (512 * 512)
#define NPIX (512 * 512)
#define PLANES 96
#define PPB 3   // planes per resample block
#define NG 32   // plane groups (PLANES/PPB)

// ---------------- table kernel: 512 entries of rad/cos/sin ----------------
__global__ __launch_bounds__(256) void table_kernel(float* __restrict__ radT,
                                                    float* __restrict__ cT,
                                                    float* __restrict__ sT) {
  const int t = blockIdx.x * 256 + threadIdx.x;  // 0..511

  // max_r = log(sqrt(512^2+512^2)/2 * 700), all in f32 steps (CR via f64)
  const float sq_f = (float)sqrt(524288.0);             // f32 sqrt (CR)
  const float half_f = sq_f * 0.5f;                     // exact
  const float prod_f = (float)((double)half_f * 700.0); // f32 mul emulated
  const float maxr_f = (float)log((double)prod_f);      // f32 log (CR)

  // rad = exp(t * max_r / 512) in f32 steps
  const float t1 = (float)((double)(float)t * (double)maxr_f); // f32 mul
  const float tt = t1 * (1.0f / 512.0f);                       // exact (pow2)
  radT[t] = (float)exp((double)tt);                            // f32 exp (CR)

  // ang = t * 2.0 * f32(pi) / 512 in f32 steps
  const float two_i = (float)(2 * t);  // exact
  const float ang1 = (float)((double)two_i * (double)(float)M_PI); // f32 mul
  const float ang = ang1 * (1.0f / 512.0f);                        // exact
  cT[t] = (float)cos((double)ang);  // f32 cos (CR)
  sT[t] = (float)sin((double)ang);  // f32 sin (CR)
}

// ---------------- resample kernel ----------------
__global__ __launch_bounds__(256) void resample_kernel(
    const float* __restrict__ in, float* __restrict__ out,
    const float* __restrict__ radT, const float* __restrict__ cT,
    const float* __restrict__ sT) {
  const int g = blockIdx.x & (NG - 1);   // plane group; g&7 = XCD partition
  const int pixblock = blockIdx.x >> 5;  // 0..1023 (tile index)

  // Block tile = 4theta x 64j; tiles: 128 theta-groups x 8 j-windows.
  // Wave w (tid>>6) covers j in [tj + 16w, +16); lane: lth = (tid>>4)&3,
  // lj = tid&15 -> wave = 4 adjacent rays x 16 consecutive j (compact patch).
  const int tid = (int)threadIdx.x;
  const int ti = ((pixblock >> 3) << 2);        // theta base of block
  const int tj = ((pixblock & 7) << 6);         // j base of block
  const int i = ti + ((tid >> 4) & 3);          // theta
  const int j = tj + ((tid >> 6) << 4) + (tid & 15);  // radius bin
  const int pix = i * 512 + j;

  const float rad = radT[j];
  const float c = cT[i];
  const float s = sT[i];

  // Native f32 ops == "exact in f64, round once" -> X,Y bit-identical to the
  // validated chain; all trunc/mask decisions follow from X,Y alone.
  const float X = __fadd_rn(256.0f, __fmul_rn(rad, c));
  const float Y = __fsub_rn(256.0f, __fmul_rn(rad, s));

  const int p0 = g * PPB;
  float* op = out + (size_t)p0 * HW + pix;

  const bool inb = (X >= 0.0f) && (X < 512.0f) && (Y >= 0.0f) && (Y < 512.0f);
  if (!inb) {
    __builtin_nontemporal_store(0.0f, op);
    __builtin_nontemporal_store(0.0f, op + HW);
    __builtin_nontemporal_store(0.0f, op + 2 * HW);
    return;
  }

  // corner indices (decisions from bit-exact X,Y) + f32 weights
  const int yd = (int)Y;  // trunc == floor for Y in [0,512)
  const int xd = (int)X;
  const int yu = min(yd + 1, 511);
  const int xu = min(xd + 1, 511);
  const float fyd = (Y - (float)yd) * (Y - (float)yd);
  const float fyu = (Y - (float)yu) * (Y - (float)yu);
  const float fxd = (X - (float)xd) * (X - (float)xd);
  const float fxu = (X - (float)xu) * (X - (float)xu);
  const float dd = fyd + fxd;
  const float du = fyd + fxu;
  const float ud = fyu + fxd;
  const float uu = fyu + fxu;
  const float inv = 1.0f / (dd + du + ud + uu);
  const float wdd = dd * inv;
  const float wdu = du * inv;
  const float wud = ud * inv;
  const float wuu = uu * inv;

  const int i00 = yd * 512 + xd;
  const int i01 = yd * 512 + xu;
  const int i10 = yu * 512 + xd;
  const int i11 = yu * 512 + xu;

  // ---- straight-line: issue ALL 12 gathers, then math, then stores ----
  const float* ip0 = in + (size_t)p0 * HW;
  const float* ip1 = ip0 + HW;
  const float* ip2 = ip1 + HW;

  const float a0_00 = ip0[i00];
  const float a0_01 = ip0[i01];
  const float a0_10 = ip0[i10];
  const float a0_11 = ip0[i11];
  const float a1_00 = ip1[i00];
  const float a1_01 = ip1[i01];
  const float a1_10 = ip1[i10];
  const float a1_11 = ip1[i11];
  const float a2_00 = ip2[i00];
  const float a2_01 = ip2[i01];
  const float a2_10 = ip2[i10];
  const float a2_11 = ip2[i11];

  const float v0 = wdd * a0_00 + wdu * a0_01 + wud * a0_10 + wuu * a0_11;
  const float v1 = wdd * a1_00 + wdu * a1_01 + wud * a1_10 + wuu * a1_11;
  const float v2 = wdd * a2_00 + wdu * a2_01 + wud * a2_10 + wuu * a2_11;

  __builtin_nontemporal_store(v0, op);
  __builtin_nontemporal_store(v1, op + HW);
  __builtin_nontemporal_store(v2, op + 2 * HW);
}

// ---------------- fallback: proven R2 monolithic kernel ----------------
__global__ __launch_bounds__(256) void logpolar_mono(
    const float* __restrict__ in, float* __restrict__ out) {
  const int pix = blockIdx.x * 256 + threadIdx.x;
  const int i = pix >> 9;
  const int j = pix & 511;

  const float sq_f = (float)sqrt(524288.0);
  const float half_f = sq_f * 0.5f;
  const float prod_f = (float)((double)half_f * 700.0);
  const float maxr_f = (float)log((double)prod_f);
  const float t1 = (float)((double)(float)j * (double)maxr_f);
  const float t = t1 * (1.0f / 512.0f);
  const float rad_f = (float)exp((double)t);
  const float two_i = (float)(2 * i);
  const float ang1 = (float)((double)two_i * (double)(float)M_PI);
  const float ang = ang1 * (1.0f / 512.0f);
  const float c_f = (float)cos((double)ang);
  const float s_f = (float)sin((double)ang);
  const float X0 = (float)((double)rad_f * (double)c_f);
  const float Y0 = (float)((double)rad_f * (double)s_f);
  const float X = (float)(256.0 + (double)X0);
  const float Y = (float)(256.0 - (double)Y0);

  const bool inb = (X >= 0.0f) && (X < 512.0f) && (Y >= 0.0f) && (Y < 512.0f);

  float wdd = 0.f, wdu = 0.f, wud = 0.f, wuu = 0.f;
  int idd = 0, idu = 0, iud = 0, iuu = 0;
  if (inb) {
    const int yd = (int)Y;
    const int xd = (int)X;
    const int yu = min(yd + 1, 511);
    const int xu = min(xd + 1, 511);
    const double Xd = (double)X, Yd = (double)Y;
    const double dyd = (Yd - (double)yd) * (Yd - (double)yd);
    const double dyu = (Yd - (double)yu) * (Yd - (double)yu);
    const double dxd = (Xd - (double)xd) * (Xd - (double)xd);
    const double dxu = (Xd - (double)xu) * (Xd - (double)xu);
    const double dd = dyd + dxd;
    const double du = dyd + dxu;
    const double ud = dyu + dxd;
    const double uu = dyu + dxu;
    const double inv = 1.0 / (dd + du + ud + uu);
    wdd = (float)(dd * inv);
    wdu = (float)(du * inv);
    wud = (float)(ud * inv);
    wuu = (float)(uu * inv);
    idd = yd * 512 + xd;
    idu = yd * 512 + xu;
    iud = yu * 512 + xd;
    iuu = yu * 512 + xu;
  }

  const float* __restrict__ ip = in;
  float* __restrict__ op = out + pix;
#pragma unroll 4
  for (int p = 0; p < PLANES; ++p) {
    float v = 0.0f;
    if (inb) {
      v = wdd * ip[idd] + wdu * ip[idu] + wud * ip[iud] + wuu * ip[iuu];
    }
    *op = v;
    ip += HW;
    op += HW;
  }
}

extern "C" void kernel_launch(void* const* d_in, const int* in_sizes, int n_in,
                              void* d_out, int out_size, void* d_ws,
                              size_t ws_size, hipStream_t stream) {
  const float* in = (const float*)d_in[0];
  float* out = (float*)d_out;

  const size_t table_bytes = 3 * 512 * sizeof(float);  // 6 KB
  if (ws_size >= table_bytes) {
    float* radT = (float*)d_ws;
    float* cT = radT + 512;
    float* sT = cT + 512;
    table_kernel<<<dim3(2), dim3(256), 0, stream>>>(radT, cT, sT);
    resample_kernel<<<dim3((NPIX / 256) * NG), dim3(256), 0, stream>>>(
        in, out, radT, cT, sT);
  } else {
    logpolar_mono<<<dim3(NPIX / 256), dim3(256), 0, stream>>>(in, out);
  }
}